// Round 1
// baseline (186.604 us; speedup 1.0000x reference)
//
#include <hip/hip_runtime.h>
#include <stdint.h>

namespace {

constexpr int H = 512, W = 512;
constexpr int PLANE = H * W;
constexpr int IMG3 = 3 * PLANE;

constexpr float U_LO = -0.44f, U_HI = 0.44f;
constexpr float V_LO = -0.62f, V_HI = 0.62f;

__device__ __forceinline__ int refl(int i, int n) {
    i = (i < 0) ? (-1 - i) : i;
    i = (i >= n) ? (2 * n - 1 - i) : i;
    return i;
}

__device__ __forceinline__ void cas(float& a, float& b) {
    float t = fminf(a, b);
    b = fmaxf(a, b);
    a = t;
}

__device__ __forceinline__ float med3(float a, float b, float c) {
    return fmaxf(fminf(a, b), fminf(fmaxf(a, b), c));
}

// 16 packed 8-bit counters across (lo, hi). counts <= 81 so no lane carry.
__device__ __forceinline__ void acc16(uint64_t& lo, uint64_t& hi, int bin, bool pred) {
    uint64_t one = 1ull << ((bin & 7) * 8);
    one = pred ? one : 0ull;
    bool l8 = bin < 8;
    lo += l8 ? one : 0ull;
    hi += l8 ? 0ull : one;
}

// find bin containing rank r (0-based), and the residual rank within it
__device__ __forceinline__ void sel16(uint64_t lo, uint64_t hi, int r, int& bin, int& rrem) {
    int run = 0, b = 0, before = 0;
#pragma unroll
    for (int j = 0; j < 16; ++j) {
        int c = (int)(((j < 8) ? (lo >> (8 * j)) : (hi >> (8 * (j - 8)))) & 0xffull);
        run += c;
        if (run <= r) { b++; before += c; }
    }
    bin = b;
    rrem = r - before;
}

__global__ __launch_bounds__(256) void denoise_kernel(const float* __restrict__ img,
                                                      float* __restrict__ out) {
    __shared__ float lumT[18][19];
    __shared__ unsigned short uvT[24][25];

    const int tx = threadIdx.x, ty = threadIdx.y;
    const int tid = ty * 16 + tx;
    const int bx = blockIdx.x, by = blockIdx.y, bz = blockIdx.z;
    const float* __restrict__ base = img + (size_t)bz * IMG3;

    // --- stage luminance tile (18x18, halo 1), computing Y on the fly ---
    for (int idx = tid; idx < 18 * 18; idx += 256) {
        int r = idx / 18, c = idx - r * 18;
        int gy = refl(by * 16 + r - 1, H);
        int gx = refl(bx * 16 + c - 1, W);
        int o = gy * W + gx;
        float R = base[o], G = base[o + PLANE], B = base[o + 2 * PLANE];
        lumT[r][c] = 0.299f * R + 0.587f * G + 0.114f * B;
    }
    // --- stage chroma key tile (24x24, halo 4), quantized to 8-bit U|V ---
    for (int idx = tid; idx < 24 * 24; idx += 256) {
        int r = idx / 24, c = idx - r * 24;
        int gy = refl(by * 16 + r - 4, H);
        int gx = refl(bx * 16 + c - 4, W);
        int o = gy * W + gx;
        float R = base[o], G = base[o + PLANE], B = base[o + 2 * PLANE];
        float U = -0.14713f * R - 0.28886f * G + 0.436f * B;
        float V = 0.615f * R - 0.51499f * G - 0.10001f * B;
        int ku = (int)floorf((U - U_LO) * (256.0f / (U_HI - U_LO)));
        int kv = (int)floorf((V - V_LO) * (256.0f / (V_HI - V_LO)));
        ku = min(max(ku, 0), 255);
        kv = min(max(kv, 0), 255);
        uvT[r][c] = (unsigned short)(ku | (kv << 8));
    }
    __syncthreads();

    // --- exact 3x3 median on Y (Paeth network) + clip ---
    float p0 = lumT[ty + 0][tx + 0], p1 = lumT[ty + 0][tx + 1], p2 = lumT[ty + 0][tx + 2];
    float p3 = lumT[ty + 1][tx + 0], p4 = lumT[ty + 1][tx + 1], p5 = lumT[ty + 1][tx + 2];
    float p6 = lumT[ty + 2][tx + 0], p7 = lumT[ty + 2][tx + 1], p8 = lumT[ty + 2][tx + 2];
    cas(p0, p1); cas(p1, p2); cas(p0, p1);
    cas(p3, p4); cas(p4, p5); cas(p3, p4);
    cas(p6, p7); cas(p7, p8); cas(p6, p7);
    float mx = fmaxf(fmaxf(p0, p3), p6);
    float md = med3(p1, p4, p7);
    float mn = fminf(fminf(p2, p5), p8);
    float Ym = med3(mx, md, mn);
    Ym = fminf(fmaxf(Ym, 0.0f), 1.0f);

    // --- 9x9 chroma median: radix select on 8-bit keys, rank 40 of 81 ---
    // pass 1: coarse (high nibble)
    uint64_t ulo = 0, uhi = 0, vlo = 0, vhi = 0;
    for (int dr = 0; dr < 9; ++dr) {
#pragma unroll
        for (int dc = 0; dc < 9; ++dc) {
            int k = uvT[ty + dr][tx + dc];
            int ku = k & 255, kv = k >> 8;
            acc16(ulo, uhi, ku >> 4, true);
            acc16(vlo, vhi, kv >> 4, true);
        }
    }
    int bu, ru, bv, rv;
    sel16(ulo, uhi, 40, bu, ru);
    sel16(vlo, vhi, 40, bv, rv);

    // pass 2: fine (low nibble) among elements in the selected coarse bin
    ulo = 0; uhi = 0; vlo = 0; vhi = 0;
    for (int dr = 0; dr < 9; ++dr) {
#pragma unroll
        for (int dc = 0; dc < 9; ++dc) {
            int k = uvT[ty + dr][tx + dc];
            int ku = k & 255, kv = k >> 8;
            acc16(ulo, uhi, ku & 15, (ku >> 4) == bu);
            acc16(vlo, vhi, kv & 15, (kv >> 4) == bv);
        }
    }
    int fu, r2u, fv, r2v;
    sel16(ulo, uhi, ru, fu, r2u);
    sel16(vlo, vhi, rv, fv, r2v);

    int keyU = (bu << 4) | fu;
    int keyV = (bv << 4) | fv;
    float Um = U_LO + ((float)keyU + 0.5f) * ((U_HI - U_LO) / 256.0f);
    float Vm = V_LO + ((float)keyV + 0.5f) * ((V_HI - V_LO) / 256.0f);

    // --- YUV -> RGB and store ---
    float Rv = Ym + 1.13983f * Vm;
    float Gv = Ym - 0.39465f * Um - 0.5806f * Vm;
    float Bv = Ym + 2.03211f * Um;

    size_t o = (size_t)bz * IMG3 + (size_t)(by * 16 + ty) * W + (bx * 16 + tx);
    out[o] = Rv;
    out[o + PLANE] = Gv;
    out[o + 2 * PLANE] = Bv;
}

} // namespace

extern "C" void kernel_launch(void* const* d_in, const int* in_sizes, int n_in,
                              void* d_out, int out_size, void* d_ws, size_t ws_size,
                              hipStream_t stream) {
    const float* img = (const float*)d_in[0];
    float* out = (float*)d_out;
    int batch = in_sizes[0] / IMG3;  // = 4
    dim3 grid(W / 16, H / 16, batch);
    dim3 block(16, 16);
    hipLaunchKernelGGL(denoise_kernel, grid, block, 0, stream, img, out);
}

// Round 2
// 109.203 us; speedup vs baseline: 1.7088x; 1.7088x over previous
//
#include <hip/hip_runtime.h>
#include <stdint.h>

namespace {

constexpr int H = 512, W = 512;
constexpr int PLANE = H * W;
constexpr int IMG3 = 3 * PLANE;

constexpr float U_LO = -0.44f, U_HI = 0.44f;
constexpr float V_LO = -0.62f, V_HI = 0.62f;

__device__ __forceinline__ int refl(int i, int n) {
    i = (i < 0) ? (-1 - i) : i;
    i = (i >= n) ? (2 * n - 1 - i) : i;
    return i;
}

__device__ __forceinline__ void cas(float& a, float& b) {
    float t = fminf(a, b);
    b = fmaxf(a, b);
    a = t;
}

__device__ __forceinline__ float med3(float a, float b, float c) {
    return fmaxf(fminf(a, b), fminf(fmaxf(a, b), c));
}

// LDS tile word layout: byte0 = min(ku,128), byte1 = min(kv,128),
//                       byte2 = max(ku-128,0), byte3 = max(kv-128,0)
__global__ __launch_bounds__(256) void denoise_kernel(const float* __restrict__ img,
                                                      float* __restrict__ out) {
    __shared__ float lumT[18][19];
    __shared__ uint32_t uvT[24][25];

    const int tx = threadIdx.x, ty = threadIdx.y;
    const int tid = ty * 16 + tx;
    const int bx = blockIdx.x, by = blockIdx.y, bz = blockIdx.z;
    const float* __restrict__ base = img + (size_t)bz * IMG3;

    // --- stage luminance tile (18x18, halo 1) ---
    for (int idx = tid; idx < 18 * 18; idx += 256) {
        int r = idx / 18, c = idx - r * 18;
        int gy = refl(by * 16 + r - 1, H);
        int gx = refl(bx * 16 + c - 1, W);
        int o = gy * W + gx;
        float R = base[o], G = base[o + PLANE], B = base[o + 2 * PLANE];
        lumT[r][c] = 0.299f * R + 0.587f * G + 0.114f * B;
    }
    // --- stage chroma key tile (24x24, halo 4), split into low/high 7-bit halves ---
    for (int idx = tid; idx < 24 * 24; idx += 256) {
        int r = idx / 24, c = idx - r * 24;
        int gy = refl(by * 16 + r - 4, H);
        int gx = refl(bx * 16 + c - 4, W);
        int o = gy * W + gx;
        float R = base[o], G = base[o + PLANE], B = base[o + 2 * PLANE];
        float U = -0.14713f * R - 0.28886f * G + 0.436f * B;
        float V = 0.615f * R - 0.51499f * G - 0.10001f * B;
        int ku = (int)floorf((U - U_LO) * (256.0f / (U_HI - U_LO)));
        int kv = (int)floorf((V - V_LO) * (256.0f / (V_HI - V_LO)));
        ku = min(max(ku, 0), 255);
        kv = min(max(kv, 0), 255);
        int kuL = min(ku, 128), kvL = min(kv, 128);
        int kuH = max(ku - 128, 0), kvH = max(kv - 128, 0);
        uvT[r][c] = (uint32_t)(kuL | (kvL << 8) | (kuH << 16) | (kvH << 24));
    }
    __syncthreads();

    // --- exact 3x3 median on Y (Paeth network) + clip ---
    float p0 = lumT[ty + 0][tx + 0], p1 = lumT[ty + 0][tx + 1], p2 = lumT[ty + 0][tx + 2];
    float p3 = lumT[ty + 1][tx + 0], p4 = lumT[ty + 1][tx + 1], p5 = lumT[ty + 1][tx + 2];
    float p6 = lumT[ty + 2][tx + 0], p7 = lumT[ty + 2][tx + 1], p8 = lumT[ty + 2][tx + 2];
    cas(p0, p1); cas(p1, p2); cas(p0, p1);
    cas(p3, p4); cas(p4, p5); cas(p3, p4);
    cas(p6, p7); cas(p7, p8); cas(p6, p7);
    float mx = fmaxf(fmaxf(p0, p3), p6);
    float md = med3(p1, p4, p7);
    float mn = fminf(fminf(p2, p5), p8);
    float Ym = med3(mx, md, mn);
    Ym = fminf(fmaxf(Ym, 0.0f), 1.0f);

    // --- gather 81 window keys into packed register arrays ---
    // PL bytes: [kuL(e0), kvL(e0), kuL(e1), kvL(e1)]  (U in bytes 0,2; V in 1,3)
    // slot 82 (high half of word 40) is a 0-sentinel: counts as <= everything,
    // so the rank threshold is 42 (= rank-40 median + 1 sentinel).
    uint32_t PL[41], PH[41];
#pragma unroll
    for (int dr = 0; dr < 9; ++dr) {
        const uint32_t* row = &uvT[ty + dr][tx];
#pragma unroll
        for (int dc = 0; dc < 9; ++dc) {
            int e = dr * 9 + dc;
            uint32_t v = row[dc];
            if ((e & 1) == 0) {
                PL[e >> 1] = v & 0xFFFFu;
                PH[e >> 1] = v >> 16;
            } else {
                PL[e >> 1] |= v << 16;
                PH[e >> 1] |= v & 0xFFFF0000u;
            }
        }
    }

    // --- step 1: resolve top bit. count(key <= 127) per channel via PL vs 0xFF ---
    uint32_t acc = 0;
#pragma unroll
    for (int i = 0; i < 41; ++i) {
        uint32_t t = (0xFFFFFFFFu - PL[i]) & 0x80808080u;
        acc += t >> 7;
    }
    uint32_t cu = (acc & 0xFFu) + ((acc >> 16) & 0xFFu);
    uint32_t cv = ((acc >> 8) & 0xFFu) + (acc >> 24);
    bool condU = (cu >= 42u);
    bool condV = (cv >= 42u);
    uint32_t M = (condU ? 0x00FF00FFu : 0u) | (condV ? 0xFF00FF00u : 0u);
#pragma unroll
    for (int i = 0; i < 41; ++i) {
        PL[i] = (PL[i] & M) | (PH[i] & ~M);  // v_bfi: per-channel half select
    }
    uint32_t baseU = condU ? 0u : 128u;
    uint32_t baseV = condV ? 0u : 128u;

    // --- 7 more steps: binary search low 7 bits, both channels per SWAR pass ---
    uint32_t lou = 0, lov = 0;
#pragma unroll
    for (int s = 64; s >= 1; s >>= 1) {
        uint32_t mu = lou + (uint32_t)(s - 1);
        uint32_t mv = lov + (uint32_t)(s - 1);
        uint32_t m4 = mu | (mv << 8);
        m4 |= m4 << 16;
        m4 += 0x80808080u;  // bytes: 0x80+m, m<=127 so no byte carry
        acc = 0;
#pragma unroll
        for (int i = 0; i < 41; ++i) {
            uint32_t t = (m4 - PL[i]) & 0x80808080u;  // bit7 set iff byte <= m
            acc += t >> 7;
        }
        cu = (acc & 0xFFu) + ((acc >> 16) & 0xFFu);
        cv = ((acc >> 8) & 0xFFu) + (acc >> 24);
        lou = (cu >= 42u) ? lou : lou + (uint32_t)s;
        lov = (cv >= 42u) ? lov : lov + (uint32_t)s;
    }

    uint32_t keyU = baseU + lou;
    uint32_t keyV = baseV + lov;
    float Um = U_LO + ((float)keyU + 0.5f) * ((U_HI - U_LO) / 256.0f);
    float Vm = V_LO + ((float)keyV + 0.5f) * ((V_HI - V_LO) / 256.0f);

    // --- YUV -> RGB and store ---
    float Rv = Ym + 1.13983f * Vm;
    float Gv = Ym - 0.39465f * Um - 0.5806f * Vm;
    float Bv = Ym + 2.03211f * Um;

    size_t o = (size_t)bz * IMG3 + (size_t)(by * 16 + ty) * W + (bx * 16 + tx);
    out[o] = Rv;
    out[o + PLANE] = Gv;
    out[o + 2 * PLANE] = Bv;
}

} // namespace

extern "C" void kernel_launch(void* const* d_in, const int* in_sizes, int n_in,
                              void* d_out, int out_size, void* d_ws, size_t ws_size,
                              hipStream_t stream) {
    const float* img = (const float*)d_in[0];
    float* out = (float*)d_out;
    int batch = in_sizes[0] / IMG3;  // = 4
    dim3 grid(W / 16, H / 16, batch);
    dim3 block(16, 16);
    hipLaunchKernelGGL(denoise_kernel, grid, block, 0, stream, img, out);
}

// Round 5
// 97.780 us; speedup vs baseline: 1.9084x; 1.1168x over previous
//
#include <hip/hip_runtime.h>
#include <stdint.h>

namespace {

constexpr int H = 512, W = 512;
constexpr int PLANE = H * W;
constexpr int IMG3 = 3 * PLANE;

// achievable ranges: U in [-0.43599, 0.436], V in [-0.615, 0.615]
constexpr float U_LO = -0.436f, U_HI = 0.436f;
constexpr float V_LO = -0.615f, V_HI = 0.615f;

constexpr int TW = 32, TH = 16;      // output tile per block (2 px/thread in x)
constexpr int CW = 40, CH = 24;      // staged tile incl. halo 4
constexpr int UVS32 = 24;            // uvT u32 row stride (u16 stride 48)
constexpr int LUMS = 45;             // lumT f32 row stride (odd: conflict-light)

__device__ __forceinline__ int refl(int i, int n) {
    i = (i < 0) ? (-1 - i) : i;
    return (i >= n) ? (2 * n - 1 - i) : i;
}
__device__ __forceinline__ void cas(float& a, float& b) {
    float t = fminf(a, b); b = fmaxf(a, b); a = t;
}
__device__ __forceinline__ float med3(float a, float b, float c) {
    return fmaxf(fminf(a, b), fminf(fmaxf(a, b), c));
}
__device__ __forceinline__ float med9(float p0, float p1, float p2, float p3, float p4,
                                      float p5, float p6, float p7, float p8) {
    cas(p0, p1); cas(p1, p2); cas(p0, p1);
    cas(p3, p4); cas(p4, p5); cas(p3, p4);
    cas(p6, p7); cas(p7, p8); cas(p6, p7);
    float mx = fmaxf(fmaxf(p0, p3), p6);
    float md = med3(p1, p4, p7);
    float mn = fminf(fminf(p2, p5), p8);
    return med3(mx, md, mn);
}

// 7-step SWAR binary search for the rank-40 median of 81 7-bit keys (+1 zero
// sentinel in slot 82 -> count threshold 42) in both byte channels at once.
// P bytes: [u(even px-elem), v, u(odd), v]. U counted from bytes 0,2; V from 1,3.
__device__ __forceinline__ void search7(const uint32_t* P, uint32_t& kU, uint32_t& kV) {
    uint32_t lou = 0, lov = 0;
#pragma unroll
    for (int s = 64; s >= 1; s >>= 1) {
        uint32_t m4 = (lou + (uint32_t)(s - 1)) | ((lov + (uint32_t)(s - 1)) << 8);
        m4 |= m4 << 16;
        m4 += 0x80808080u;  // per-byte 0x80+m, m<=127, keys<=127 -> borrow-free
        uint32_t acc = 0;
#pragma unroll
        for (int i = 0; i < 41; ++i)
            acc += ((m4 - P[i]) & 0x80808080u) >> 7;  // bit7 set iff byte <= m
        uint32_t cu = (acc & 0xFFu) + ((acc >> 16) & 0xFFu);
        uint32_t cv = ((acc >> 8) & 0xFFu) + (acc >> 24);
        if (cu < 42u) lou += (uint32_t)s;
        if (cv < 42u) lov += (uint32_t)s;
    }
    kU = lou; kV = lov;
}

__global__ __launch_bounds__(256) void denoise_kernel(const float* __restrict__ img,
                                                      float* __restrict__ out) {
    __shared__ uint32_t uvT[CH * UVS32];   // packed u16 keys (ku | kv<<8)
    __shared__ float lumT[CH * LUMS];

    const int tid = threadIdx.x;
    const int tx = tid & 15, ty = tid >> 4;
    const int bx = blockIdx.x, by = blockIdx.y, bz = blockIdx.z;
    const float* __restrict__ base = img + (size_t)bz * IMG3;

    // --- single staging pass: Y + quantized 7-bit UV keys for the 40x24 tile ---
    uint16_t* uv16 = (uint16_t*)uvT;
    {
        // 960 elements, 256 threads: iterations idx = tid, tid+256, ..., < 960
        int idx = tid;
#pragma unroll 4
        for (int it = 0; it < 4; ++it) {
            if (idx < CW * CH) {
                int r = idx / CW, c = idx - r * CW;
                int gy = refl(by * TH + r - 4, H);
                int gx = refl(bx * TW + c - 4, W);
                int o = gy * W + gx;
                float R = base[o], G = base[o + PLANE], B = base[o + 2 * PLANE];
                float Y = 0.299f * R + 0.587f * G + 0.114f * B;
                float U = -0.14713f * R - 0.28886f * G + 0.436f * B;
                float V = 0.615f * R - 0.51499f * G - 0.10001f * B;
                int ku = (int)((U - U_LO) * (128.0f / (U_HI - U_LO)));
                int kv = (int)((V - V_LO) * (128.0f / (V_HI - V_LO)));
                ku = min(max(ku, 0), 127);
                kv = min(max(kv, 0), 127);
                lumT[r * LUMS + c] = Y;
                uv16[r * 48 + c] = (uint16_t)(ku | (kv << 8));
            }
            idx += 256;
        }
    }
    __syncthreads();

    // --- chroma median, pixel A (x = bx*32 + 2*tx): u16 cols 2tx..2tx+8 ---
    uint32_t P[41];
    uint32_t pend = 0;
#pragma unroll
    for (int r = 0; r < 9; ++r) {
        const uint32_t* row = &uvT[(ty + r) * UVS32 + tx];
        uint32_t w0 = row[0], w1 = row[1], w2 = row[2], w3 = row[3], w4 = row[4];
        P[r * 4 + 0] = w0; P[r * 4 + 1] = w1;
        P[r * 4 + 2] = w2; P[r * 4 + 3] = w3;
        if ((r & 1) == 0) pend = w4 & 0xFFFFu;
        else              P[36 + (r >> 1)] = pend | (w4 << 16);
    }
    P[40] = pend;  // r=8 leftover; high 16 bits = 0 sentinel
    uint32_t kUA, kVA;
    search7(P, kUA, kVA);

    // --- pixel B (x+1): u16 cols 2tx+1..2tx+9 ---
#pragma unroll
    for (int r = 0; r < 9; ++r) {
        const uint32_t* row = &uvT[(ty + r) * UVS32 + tx];
        uint32_t w0 = row[0], w1 = row[1], w2 = row[2], w3 = row[3], w4 = row[4];
        P[r * 4 + 0] = (w0 >> 16) | (w1 << 16);
        P[r * 4 + 1] = (w1 >> 16) | (w2 << 16);
        P[r * 4 + 2] = (w2 >> 16) | (w3 << 16);
        P[r * 4 + 3] = (w3 >> 16) | (w4 << 16);
        if ((r & 1) == 0) pend = w4 >> 16;
        else              P[36 + (r >> 1)] = pend | (w4 & 0xFFFF0000u);
    }
    P[40] = pend;
    uint32_t kUB, kVB;
    search7(P, kUB, kVB);

    // --- 3x3 lum median for both pixels (rows ty+3..ty+5, cols 2tx+3..2tx+6) ---
    const float* lr0 = &lumT[(ty + 3) * LUMS + 2 * tx + 3];
    const float* lr1 = lr0 + LUMS;
    const float* lr2 = lr1 + LUMS;
    float a0 = lr0[0], a1 = lr0[1], a2 = lr0[2], a3 = lr0[3];
    float b0 = lr1[0], b1 = lr1[1], b2 = lr1[2], b3 = lr1[3];
    float c0 = lr2[0], c1 = lr2[1], c2 = lr2[2], c3 = lr2[3];
    float YmA = fminf(fmaxf(med9(a0, a1, a2, b0, b1, b2, c0, c1, c2), 0.0f), 1.0f);
    float YmB = fminf(fmaxf(med9(a1, a2, a3, b1, b2, b3, c1, c2, c3), 0.0f), 1.0f);

    // --- dequant (bin centers) + YUV->RGB + store ---
    const float us = (U_HI - U_LO) / 128.0f, vs = (V_HI - V_LO) / 128.0f;
    float UmA = U_LO + ((float)kUA + 0.5f) * us;
    float VmA = V_LO + ((float)kVA + 0.5f) * vs;
    float UmB = U_LO + ((float)kUB + 0.5f) * us;
    float VmB = V_LO + ((float)kVB + 0.5f) * vs;

    size_t o = (size_t)bz * IMG3 + (size_t)(by * TH + ty) * W + (bx * TW + 2 * tx);
    out[o] = YmA + 1.13983f * VmA;
    out[o + 1] = YmB + 1.13983f * VmB;
    out[o + PLANE] = YmA - 0.39465f * UmA - 0.5806f * VmA;
    out[o + PLANE + 1] = YmB - 0.39465f * UmB - 0.5806f * VmB;
    out[o + 2 * PLANE] = YmA + 2.03211f * UmA;
    out[o + 2 * PLANE + 1] = YmB + 2.03211f * UmB;
}

} // namespace

extern "C" void kernel_launch(void* const* d_in, const int* in_sizes, int n_in,
                              void* d_out, int out_size, void* d_ws, size_t ws_size,
                              hipStream_t stream) {
    const float* img = (const float*)d_in[0];
    float* out = (float*)d_out;
    int batch = in_sizes[0] / IMG3;  // = 4
    dim3 grid(W / TW, H / TH, batch);
    dim3 block(256);
    hipLaunchKernelGGL(denoise_kernel, grid, block, 0, stream, img, out);
}

// Round 6
// 95.470 us; speedup vs baseline: 1.9546x; 1.0242x over previous
//
#include <hip/hip_runtime.h>
#include <stdint.h>

namespace {

constexpr int H = 512, W = 512;
constexpr int PLANE = H * W;
constexpr int IMG3 = 3 * PLANE;

constexpr float U_LO = -0.436f, U_HI = 0.436f;
constexpr float V_LO = -0.615f, V_HI = 0.615f;

constexpr int TW = 32, TH = 16;   // output tile per block (2 px/thread in x)
constexpr int CW = 40, CH = 24;   // staged tile incl. halo 4
constexpr int US = 13;            // u32 stride of U/V byte planes (52 B, 40 used)
constexpr int LUMS = 45;          // lumT f32 row stride

__device__ __forceinline__ int refl(int i, int n) {
    i = (i < 0) ? (-1 - i) : i;
    return (i >= n) ? (2 * n - 1 - i) : i;
}
__device__ __forceinline__ void cas(float& a, float& b) {
    float t = fminf(a, b); b = fmaxf(a, b); a = t;
}
__device__ __forceinline__ float med3(float a, float b, float c) {
    return fmaxf(fminf(a, b), fminf(fmaxf(a, b), c));
}
__device__ __forceinline__ float med9(float p0, float p1, float p2, float p3, float p4,
                                      float p5, float p6, float p7, float p8) {
    cas(p0, p1); cas(p1, p2); cas(p0, p1);
    cas(p3, p4); cas(p4, p5); cas(p3, p4);
    cas(p6, p7); cas(p7, p8); cas(p6, p7);
    float mx = fmaxf(fmaxf(p0, p3), p6);
    float md = med3(p1, p4, p7);
    float mn = fminf(fminf(p2, p5), p8);
    return med3(mx, md, mn);
}

// funnel shift: bytes of (w1:w0) starting at byte sh/8 (sh in {0,8,16,24})
__device__ __forceinline__ uint32_t fsh(uint32_t w1, uint32_t w0, uint32_t sh) {
    return (uint32_t)(((((uint64_t)w1) << 32) | w0) >> sh);  // -> v_alignbit_b32
}

// rank-select over 84 bytes (81 keys <=127 + 3 always-counting 0-pads) packed
// in 21 u32s. Returns smallest m with count(key <= m) >= 44 (= rank 40 + pads).
__device__ __forceinline__ uint32_t search7p(const uint32_t* P) {
    uint32_t lo = 0;
#pragma unroll
    for (int s = 64; s >= 1; s >>= 1) {
        uint32_t m = lo + (uint32_t)(s - 1);
        uint32_t c4 = m * 0x01010101u + 0x80808080u;  // per-byte 0x80+m, borrow-free
        uint32_t acc = 0;
#pragma unroll
        for (int i = 0; i < 21; ++i) {
            uint32_t t = (c4 - P[i]) & 0x80808080u;  // bit7 set iff byte <= m
#if __has_builtin(__builtin_amdgcn_sad_u8)
            acc = __builtin_amdgcn_sad_u8(t, 0u, acc);  // acc += 0x80 * count
#else
            acc += t >> 7;  // per-byte-lane counts (<= 21 each)
#endif
        }
#if __has_builtin(__builtin_amdgcn_sad_u8)
        uint32_t cnt = acc >> 7;
#else
        uint32_t cnt = (acc * 0x01010101u) >> 24;  // horizontal byte sum
#endif
        if (cnt < 44u) lo += (uint32_t)s;
    }
    return lo;
}

// gather one channel's A/B windows (pixel pair) from a byte plane and select
__device__ __forceinline__ void chan_medians(const uint32_t* plane, int tx, int ty,
                                             uint32_t& kA, uint32_t& kB) {
    uint32_t PA[21], PB[21];
    const uint32_t sh = (uint32_t)((tx & 1) << 4);  // 0 or 16
    uint32_t la01 = 0, la2 = 0, lb01 = 0, lb2 = 0;
    uint32_t la1 = 0, lb1 = 0;
#pragma unroll
    for (int r = 0; r < 9; ++r) {
        const uint32_t* row = plane + (ty + r) * US + (tx >> 1);
        uint32_t w0 = row[0], w1 = row[1], w2 = row[2];
        PA[2 * r] = fsh(w1, w0, sh);
        PA[2 * r + 1] = fsh(w2, w1, sh);
        PB[2 * r] = fsh(w1, w0, sh + 8);
        PB[2 * r + 1] = fsh(w2, w1, sh + 8);
        uint32_t la = (w2 >> sh) & 0xFFu;         // A's 9th byte of row
        uint32_t lb = (w2 >> (sh + 8)) & 0xFFu;   // B's 9th byte of row
        if (r < 4)      { la01 |= la << (8 * r);       lb01 |= lb << (8 * r); }
        else if (r < 8) { la1  |= la << (8 * (r - 4)); lb1  |= lb << (8 * (r - 4)); }
        else            { la2 = la;                    lb2 = lb; }
    }
    PA[18] = la01; PA[19] = la1; PA[20] = la2;  // pads are 0x00 (always count)
    PB[18] = lb01; PB[19] = lb1; PB[20] = lb2;
    kA = search7p(PA);
    kB = search7p(PB);
}

__global__ __launch_bounds__(256, 4) void denoise_kernel(const float* __restrict__ img,
                                                         float* __restrict__ out) {
    __shared__ uint32_t uP[CH * US];
    __shared__ uint32_t vP[CH * US];
    __shared__ float lumT[CH * LUMS];

    const int tid = threadIdx.x;
    const int tx = tid & 15, ty = tid >> 4;
    const int bx = blockIdx.x, by = blockIdx.y, bz = blockIdx.z;
    const float* __restrict__ base = img + (size_t)bz * IMG3;

    // --- staging: Y (f32) + quantized 7-bit U,V byte planes for 40x24 tile ---
    uint8_t* u8p = (uint8_t*)uP;
    uint8_t* v8p = (uint8_t*)vP;
    {
        int idx = tid;
#pragma unroll 4
        for (int it = 0; it < 4; ++it) {
            if (idx < CW * CH) {
                int r = idx / CW, c = idx - r * CW;
                int gy = refl(by * TH + r - 4, H);
                int gx = refl(bx * TW + c - 4, W);
                int o = gy * W + gx;
                float R = base[o], G = base[o + PLANE], B = base[o + 2 * PLANE];
                float Y = 0.299f * R + 0.587f * G + 0.114f * B;
                float U = -0.14713f * R - 0.28886f * G + 0.436f * B;
                float V = 0.615f * R - 0.51499f * G - 0.10001f * B;
                int ku = (int)((U - U_LO) * (128.0f / (U_HI - U_LO)));
                int kv = (int)((V - V_LO) * (128.0f / (V_HI - V_LO)));
                ku = min(max(ku, 0), 127);
                kv = min(max(kv, 0), 127);
                lumT[r * LUMS + c] = Y;
                u8p[r * (US * 4) + c] = (uint8_t)ku;
                v8p[r * (US * 4) + c] = (uint8_t)kv;
            }
            idx += 256;
        }
    }
    __syncthreads();

    // --- chroma medians: U channel (both pixels), then V channel ---
    uint32_t kUA, kUB, kVA, kVB;
    chan_medians(uP, tx, ty, kUA, kUB);
    chan_medians(vP, tx, ty, kVA, kVB);

    // --- 3x3 lum median for both pixels ---
    const float* lr0 = &lumT[(ty + 3) * LUMS + 2 * tx + 3];
    const float* lr1 = lr0 + LUMS;
    const float* lr2 = lr1 + LUMS;
    float a0 = lr0[0], a1 = lr0[1], a2 = lr0[2], a3 = lr0[3];
    float b0 = lr1[0], b1 = lr1[1], b2 = lr1[2], b3 = lr1[3];
    float c0 = lr2[0], c1 = lr2[1], c2 = lr2[2], c3 = lr2[3];
    float YmA = fminf(fmaxf(med9(a0, a1, a2, b0, b1, b2, c0, c1, c2), 0.0f), 1.0f);
    float YmB = fminf(fmaxf(med9(a1, a2, a3, b1, b2, b3, c1, c2, c3), 0.0f), 1.0f);

    // --- dequant (bin centers) + YUV->RGB + store ---
    const float us = (U_HI - U_LO) / 128.0f, vs = (V_HI - V_LO) / 128.0f;
    float UmA = U_LO + ((float)kUA + 0.5f) * us;
    float VmA = V_LO + ((float)kVA + 0.5f) * vs;
    float UmB = U_LO + ((float)kUB + 0.5f) * us;
    float VmB = V_LO + ((float)kVB + 0.5f) * vs;

    size_t o = (size_t)bz * IMG3 + (size_t)(by * TH + ty) * W + (bx * TW + 2 * tx);
    out[o] = YmA + 1.13983f * VmA;
    out[o + 1] = YmB + 1.13983f * VmB;
    out[o + PLANE] = YmA - 0.39465f * UmA - 0.5806f * VmA;
    out[o + PLANE + 1] = YmB - 0.39465f * UmB - 0.5806f * VmB;
    out[o + 2 * PLANE] = YmA + 2.03211f * UmA;
    out[o + 2 * PLANE + 1] = YmB + 2.03211f * UmB;
}

} // namespace

extern "C" void kernel_launch(void* const* d_in, const int* in_sizes, int n_in,
                              void* d_out, int out_size, void* d_ws, size_t ws_size,
                              hipStream_t stream) {
    const float* img = (const float*)d_in[0];
    float* out = (float*)d_out;
    int batch = in_sizes[0] / IMG3;  // = 4
    dim3 grid(W / TW, H / TH, batch);
    dim3 block(256);
    hipLaunchKernelGGL(denoise_kernel, grid, block, 0, stream, img, out);
}

// Round 8
// 94.421 us; speedup vs baseline: 1.9763x; 1.0111x over previous
//
#include <hip/hip_runtime.h>
#include <stdint.h>

namespace {

constexpr int H = 512, W = 512;
constexpr int PLANE = H * W;
constexpr int IMG3 = 3 * PLANE;

constexpr float U_LO = -0.436f, U_HI = 0.436f;
constexpr float V_LO = -0.615f, V_HI = 0.615f;

constexpr int TW = 32, TH = 16;   // output tile per block (2 px/thread in x)
constexpr int CW = 40, CH = 24;   // staged tile incl. halo 4
constexpr int US = 13;            // u32 stride of U/V byte planes (52 B, 40 used)
constexpr int LUMS = 45;          // lumT f32 row stride

__device__ __forceinline__ int refl(int i, int n) {
    i = (i < 0) ? (-1 - i) : i;
    return (i >= n) ? (2 * n - 1 - i) : i;
}
__device__ __forceinline__ void cas(float& a, float& b) {
    float t = fminf(a, b); b = fmaxf(a, b); a = t;
}
__device__ __forceinline__ float med3(float a, float b, float c) {
    return fmaxf(fminf(a, b), fminf(fmaxf(a, b), c));
}
__device__ __forceinline__ float med9(float p0, float p1, float p2, float p3, float p4,
                                      float p5, float p6, float p7, float p8) {
    cas(p0, p1); cas(p1, p2); cas(p0, p1);
    cas(p3, p4); cas(p4, p5); cas(p3, p4);
    cas(p6, p7); cas(p7, p8); cas(p6, p7);
    float mx = fmaxf(fmaxf(p0, p3), p6);
    float md = med3(p1, p4, p7);
    float mn = fminf(fminf(p2, p5), p8);
    return med3(mx, md, mn);
}

// funnel shift: bytes of (w1:w0) starting at byte sh/8
__device__ __forceinline__ uint32_t fsh(uint32_t w1, uint32_t w0, uint32_t sh) {
    return (uint32_t)(((((uint64_t)w1) << 32) | w0) >> sh);  // -> v_alignbit_b32
}

__device__ __forceinline__ uint32_t sadacc(uint32_t t, uint32_t acc) {
#if __has_builtin(__builtin_amdgcn_sad_u8)
    return __builtin_amdgcn_sad_u8(t, 0u, acc);  // acc += 0x80 * popcnt_bytes
#else
    return acc + (t >> 7);                        // per-byte-lane counts
#endif
}
__device__ __forceinline__ uint32_t cntscaled(uint32_t acc) {
#if __has_builtin(__builtin_amdgcn_sad_u8)
    return acc;                                   // already 128*count
#else
    return ((acc * 0x01010101u) >> 24) << 7;      // normalize to 128*count
#endif
}

// gather one channel's A/B windows (81 bytes + 3 zero pads in 21 u32) for the
// horizontally-adjacent pixel pair from a byte plane
__device__ __forceinline__ void gather(const uint32_t* plane, int tx, int ty,
                                       uint32_t* PA, uint32_t* PB) {
    const uint32_t sh = (uint32_t)((tx & 1) << 4);  // 0 or 16
    uint32_t la01 = 0, la1 = 0, la2 = 0, lb01 = 0, lb1 = 0, lb2 = 0;
#pragma unroll
    for (int r = 0; r < 9; ++r) {
        const uint32_t* row = plane + (ty + r) * US + (tx >> 1);
        uint32_t w0 = row[0], w1 = row[1], w2 = row[2];
        PA[2 * r] = fsh(w1, w0, sh);
        PA[2 * r + 1] = fsh(w2, w1, sh);
        PB[2 * r] = fsh(w1, w0, sh + 8);
        PB[2 * r + 1] = fsh(w2, w1, sh + 8);
        uint32_t la = (w2 >> sh) & 0xFFu;         // A's 9th byte of row
        uint32_t lb = (w2 >> (sh + 8)) & 0xFFu;   // B's 9th byte of row
        if (r < 4)      { la01 |= la << (8 * r);       lb01 |= lb << (8 * r); }
        else if (r < 8) { la1  |= la << (8 * (r - 4)); lb1  |= lb << (8 * (r - 4)); }
        else            { la2 = la;                    lb2 = lb; }
    }
    PA[18] = la01; PA[19] = la1; PA[20] = la2;  // pads are 0x00 (always count)
    PB[18] = lb01; PB[19] = lb1; PB[20] = lb2;
}

// four interleaved 7-step rank selections (rank 40 of 81 + 3 pads -> count 44)
__device__ __forceinline__ void search4(const uint32_t* __restrict__ P0,
                                        const uint32_t* __restrict__ P1,
                                        const uint32_t* __restrict__ P2,
                                        const uint32_t* __restrict__ P3,
                                        uint32_t& k0, uint32_t& k1,
                                        uint32_t& k2, uint32_t& k3) {
    uint32_t lo0 = 0, lo1 = 0, lo2 = 0, lo3 = 0;
    // SWAR threshold word: per byte 0x80 + m, m starts at 63
    uint32_t c0 = 0xBFBFBFBFu, c1 = 0xBFBFBFBFu, c2 = 0xBFBFBFBFu, c3 = 0xBFBFBFBFu;
    const uint32_t T = 44u * 128u;
#pragma unroll
    for (int s = 64; s >= 1; s >>= 1) {
        uint32_t a0 = 0, a1 = 0, a2 = 0, a3 = 0;
#pragma unroll
        for (int i = 0; i < 21; ++i) {
            a0 = sadacc((c0 - P0[i]) & 0x80808080u, a0);
            a1 = sadacc((c1 - P1[i]) & 0x80808080u, a1);
            a2 = sadacc((c2 - P2[i]) & 0x80808080u, a2);
            a3 = sadacc((c3 - P3[i]) & 0x80808080u, a3);
        }
        bool r0 = cntscaled(a0) < T;  // median above m -> go right
        bool r1 = cntscaled(a1) < T;
        bool r2 = cntscaled(a2) < T;
        bool r3 = cntscaled(a3) < T;
        lo0 += r0 ? (uint32_t)s : 0u;
        lo1 += r1 ? (uint32_t)s : 0u;
        lo2 += r2 ? (uint32_t)s : 0u;
        lo3 += r3 ? (uint32_t)s : 0u;
        if (s > 1) {
            const uint32_t d = (uint32_t)(s >> 1) * 0x01010101u;  // compile-time
            c0 = r0 ? c0 + d : c0 - d;
            c1 = r1 ? c1 + d : c1 - d;
            c2 = r2 ? c2 + d : c2 - d;
            c3 = r3 ? c3 + d : c3 - d;
        }
    }
    k0 = lo0; k1 = lo1; k2 = lo2; k3 = lo3;
}

__global__ __launch_bounds__(256, 4) void denoise_kernel(const float* __restrict__ img,
                                                         float* __restrict__ out) {
    __shared__ uint32_t uP[CH * US];
    __shared__ uint32_t vP[CH * US];
    __shared__ float lumT[CH * LUMS];

    const int tid = threadIdx.x;
    const int tx = tid & 15, ty = tid >> 4;
    const int bx = blockIdx.x, by = blockIdx.y, bz = blockIdx.z;
    const float* __restrict__ base = img + (size_t)bz * IMG3;

    // --- staging: Y (f32) + quantized 7-bit U,V byte planes for 40x24 tile ---
    uint8_t* u8p = (uint8_t*)uP;
    uint8_t* v8p = (uint8_t*)vP;
    {
        int idx = tid;
#pragma unroll 4
        for (int it = 0; it < 4; ++it) {
            if (idx < CW * CH) {
                int r = idx / CW, c = idx - r * CW;
                int gy = refl(by * TH + r - 4, H);
                int gx = refl(bx * TW + c - 4, W);
                int o = gy * W + gx;
                float R = base[o], G = base[o + PLANE], B = base[o + 2 * PLANE];
                float Y = 0.299f * R + 0.587f * G + 0.114f * B;
                float U = -0.14713f * R - 0.28886f * G + 0.436f * B;
                float V = 0.615f * R - 0.51499f * G - 0.10001f * B;
                int ku = (int)((U - U_LO) * (128.0f / (U_HI - U_LO)));
                int kv = (int)((V - V_LO) * (128.0f / (V_HI - V_LO)));
                ku = min(max(ku, 0), 127);
                kv = min(max(kv, 0), 127);
                lumT[r * LUMS + c] = Y;
                u8p[r * (US * 4) + c] = (uint8_t)ku;
                v8p[r * (US * 4) + c] = (uint8_t)kv;
            }
            idx += 256;
        }
    }
    __syncthreads();

    // --- gather all four windows, then run the four selections interleaved ---
    uint32_t PUA[21], PUB[21], PVA[21], PVB[21];
    gather(uP, tx, ty, PUA, PUB);
    gather(vP, tx, ty, PVA, PVB);
    uint32_t kUA, kUB, kVA, kVB;
    search4(PUA, PUB, PVA, PVB, kUA, kUB, kVA, kVB);

    // --- 3x3 lum median for both pixels ---
    const float* lr0 = &lumT[(ty + 3) * LUMS + 2 * tx + 3];
    const float* lr1 = lr0 + LUMS;
    const float* lr2 = lr1 + LUMS;
    float a0 = lr0[0], a1 = lr0[1], a2 = lr0[2], a3 = lr0[3];
    float b0 = lr1[0], b1 = lr1[1], b2 = lr1[2], b3 = lr1[3];
    float c0 = lr2[0], c1 = lr2[1], c2 = lr2[2], c3 = lr2[3];
    float YmA = fminf(fmaxf(med9(a0, a1, a2, b0, b1, b2, c0, c1, c2), 0.0f), 1.0f);
    float YmB = fminf(fmaxf(med9(a1, a2, a3, b1, b2, b3, c1, c2, c3), 0.0f), 1.0f);

    // --- dequant (bin centers) + YUV->RGB + store ---
    const float us = (U_HI - U_LO) / 128.0f, vs = (V_HI - V_LO) / 128.0f;
    float UmA = U_LO + ((float)kUA + 0.5f) * us;
    float VmA = V_LO + ((float)kVA + 0.5f) * vs;
    float UmB = U_LO + ((float)kUB + 0.5f) * us;
    float VmB = V_LO + ((float)kVB + 0.5f) * vs;

    size_t o = (size_t)bz * IMG3 + (size_t)(by * TH + ty) * W + (bx * TW + 2 * tx);
    out[o] = YmA + 1.13983f * VmA;
    out[o + 1] = YmB + 1.13983f * VmB;
    out[o + PLANE] = YmA - 0.39465f * UmA - 0.5806f * VmA;
    out[o + PLANE + 1] = YmB - 0.39465f * UmB - 0.5806f * VmB;
    out[o + 2 * PLANE] = YmA + 2.03211f * UmA;
    out[o + 2 * PLANE + 1] = YmB + 2.03211f * UmB;
}

} // namespace

extern "C" void kernel_launch(void* const* d_in, const int* in_sizes, int n_in,
                              void* d_out, int out_size, void* d_ws, size_t ws_size,
                              hipStream_t stream) {
    const float* img = (const float*)d_in[0];
    float* out = (float*)d_out;
    int batch = in_sizes[0] / IMG3;  // = 4
    dim3 grid(W / TW, H / TH, batch);
    dim3 block(256);
    hipLaunchKernelGGL(denoise_kernel, grid, block, 0, stream, img, out);
}